// Round 11
// baseline (249.523 us; speedup 1.0000x reference)
//
#include <hip/hip_runtime.h>
#include <hip/hip_bf16.h>

// CrossLocal: B=4, C=64, CI=32, cross 64x64 (Nc=4096), main 128x128.
// R21: attn_combine folded into attn_part's tail via last-block-combines
// (threadfence reduction: 128 counters, 8 adds each -- NOT R15's contended
// pattern). 8th arriving eighth-block re-reads the group's pnum/pden
// (L2-warm), does divide + W conv + pstats, reusing redbuf LDS as obuf.
// Counters zeroed by qkv (stream-ordered -> replay-safe). 3 launches.
// Rest = R20: 8-way key split 3 blocks/CU, fragment-major K/V (R18),
// 4 q-tiles/block (R17), coalesced qkv V-writes (R19a), no hot atomics.
// ws: Qb[1MB] Kf[1MB] Vf[1MB] out2[4MB] pnum[16MB] pden[512KB]
//     pstats[256KB] cnt[128 u32]

typedef __attribute__((ext_vector_type(8))) short bf16x8;
typedef __attribute__((ext_vector_type(4))) float f32x4;
typedef __attribute__((ext_vector_type(16))) float f32x16;

#define LOG2E 1.4426950408889634f

static __device__ __forceinline__ unsigned short f2bf_bits(float x) {
    __hip_bfloat16 h = __float2bfloat16(x);
    return *(unsigned short*)&h;
}
static __device__ __forceinline__ unsigned int pk2bf(float a, float b) {
    __hip_bfloat162 h = __float22bfloat162_rn(make_float2(a, b));
    return *(unsigned int*)&h;
}

// exp2 all 16 S entries, accumulate denominator, pack to two bf16x8 A-frags.
static __device__ __forceinline__ void softmax_pack(
    const f32x16& s, float& den, bf16x8& ap1, bf16x8& ap2)
{
    float e[16];
#pragma unroll
    for (int r = 0; r < 16; ++r) e[r] = __builtin_amdgcn_exp2f(s[r]);
    den += (((e[0]+e[1])+(e[2]+e[3])) + ((e[4]+e[5])+(e[6]+e[7])))
         + (((e[8]+e[9])+(e[10]+e[11])) + ((e[12]+e[13])+(e[14]+e[15])));
    uint4 t1 = make_uint4(pk2bf(e[0],e[1]), pk2bf(e[2],e[3]),
                          pk2bf(e[4],e[5]), pk2bf(e[6],e[7]));
    uint4 t2 = make_uint4(pk2bf(e[8],e[9]), pk2bf(e[10],e[11]),
                          pk2bf(e[12],e[13]), pk2bf(e[14],e[15]));
    ap1 = *(bf16x8*)&t1; ap2 = *(bf16x8*)&t2;
}

// ---------------- Kernel 1: Q,K,V prep (coalesced fragment-major writes) ------
__global__ __launch_bounds__(256) void qkv_kernel(
    const float* __restrict__ cross, const float* __restrict__ mainf,
    const float* __restrict__ g_w,  const float* __restrict__ g_b,
    const float* __restrict__ th_w, const float* __restrict__ th_b,
    const float* __restrict__ ph_w, const float* __restrict__ ph_b,
    __hip_bfloat16* __restrict__ Qb, __hip_bfloat16* __restrict__ Kf,
    __hip_bfloat16* __restrict__ Vf, unsigned int* __restrict__ cnt)
{
    __shared__ __align__(16) float xs[64][128];   // 32 KB
    const int kind = blockIdx.x >> 7;        // 0=Q,1=K,2=V
    const int sub  = blockIdx.x & 127;
    const int b    = sub >> 5;
    const int n0   = (sub & 31) << 7;        // 128 pixels per block
    const int tid  = threadIdx.x;
    const float* w  = (kind == 0) ? g_w : (kind == 1) ? th_w : ph_w;
    const float* bs = (kind == 0) ? g_b : (kind == 1) ? th_b : ph_b;

    if (blockIdx.x == 0 && tid < 128) cnt[tid] = 0;   // combine counters

    if (kind < 2) {
        const float* src = cross + (((size_t)(b * 64)) << 12) + n0;
        const int jr = (tid & 31) << 2, c0 = tid >> 5;
#pragma unroll
        for (int it = 0; it < 8; ++it) {
            int c = (it << 3) | c0;
            *(float4*)&xs[c][jr] = *(const float4*)(src + ((size_t)c << 12) + jr);
        }
    } else {
        const int px = tid & 127, chh = tid >> 7;
        const int n = n0 + px;
        const int i2 = (n >> 6) << 1, j2 = (n & 63) << 1;
        const float* src = mainf + (((size_t)(b * 64)) << 14) + i2 * 128 + j2;
#pragma unroll 4
        for (int cc = 0; cc < 32; ++cc) {
            int c = (chh << 5) | cc;
            const float2 a = *(const float2*)(src + ((size_t)c << 14));
            const float2 d = *(const float2*)(src + ((size_t)c << 14) + 128);
            xs[c][px] = 0.25f * ((a.x + a.y) + (d.x + d.y));
        }
    }
    __syncthreads();

    if (kind < 2) {
        const int px = tid & 127, cih = tid >> 7, ci0 = cih << 4;
        float acc[16];
#pragma unroll
        for (int j = 0; j < 16; ++j) acc[j] = bs[ci0 + j];
#pragma unroll 4
        for (int c = 0; c < 64; ++c) {
            float x = xs[c][px];
#pragma unroll
            for (int j = 0; j < 16; ++j)
                acc[j] = fmaf(w[((ci0 + j) << 6) + c], x, acc[j]);
        }
        const int n = n0 + px;
        const int chunk = n >> 5, kk = n & 31;
        if (kind == 0) {
#pragma unroll
            for (int j = 0; j < 16; ++j) acc[j] *= LOG2E;
            unsigned int u[8];
#pragma unroll
            for (int i = 0; i < 8; ++i)
                u[i] = (unsigned int)f2bf_bits(acc[2 * i]) |
                       ((unsigned int)f2bf_bits(acc[2 * i + 1]) << 16);
            uint4* d4 = (uint4*)(Qb + (size_t)((b << 12) + n) * 32 + ci0);
            d4[0] = make_uint4(u[0], u[1], u[2], u[3]);
            d4[1] = make_uint4(u[4], u[5], u[6], u[7]);
        } else {
            // K fragment-major: frag(j=cih, lane=h'*32+sig(kk)) <- ci0+8h'..+7
            unsigned int u[8];
#pragma unroll
            for (int i = 0; i < 8; ++i)
                u[i] = (unsigned int)f2bf_bits(acc[2 * i]) |
                       ((unsigned int)f2bf_bits(acc[2 * i + 1]) << 16);
            const int q = (kk & ~12) | ((kk & 4) << 1) | ((kk & 8) >> 1);  // sigma
            char* base = (char*)Kf + ((((size_t)(b << 7) | chunk) << 11) | (cih << 10));
            *(uint4*)(base + (q << 4))          = make_uint4(u[0], u[1], u[2], u[3]);
            *(uint4*)(base + ((32 + q) << 4))   = make_uint4(u[4], u[5], u[6], u[7]);
        }
    } else {
        // V: thread = (ci pair, key octet) -> 2 coalesced 16B fragment stores
        const int cip = tid & 15, o = tid >> 4;     // o in 0..15
        const int c0 = cip << 1;
        const int pxb = o << 3;
        float a0[8], a1[8];
        const float b0 = bs[c0], b1 = bs[c0 + 1];
#pragma unroll
        for (int i = 0; i < 8; ++i) { a0[i] = b0; a1[i] = b1; }
#pragma unroll 4
        for (int c = 0; c < 64; ++c) {
            const float w0 = w[(c0 << 6) + c], w1 = w[((c0 + 1) << 6) + c];
            const float4 xa = *(const float4*)&xs[c][pxb];
            const float4 xb = *(const float4*)&xs[c][pxb + 4];
            a0[0] = fmaf(w0, xa.x, a0[0]); a0[1] = fmaf(w0, xa.y, a0[1]);
            a0[2] = fmaf(w0, xa.z, a0[2]); a0[3] = fmaf(w0, xa.w, a0[3]);
            a0[4] = fmaf(w0, xb.x, a0[4]); a0[5] = fmaf(w0, xb.y, a0[5]);
            a0[6] = fmaf(w0, xb.z, a0[6]); a0[7] = fmaf(w0, xb.w, a0[7]);
            a1[0] = fmaf(w1, xa.x, a1[0]); a1[1] = fmaf(w1, xa.y, a1[1]);
            a1[2] = fmaf(w1, xa.z, a1[2]); a1[3] = fmaf(w1, xa.w, a1[3]);
            a1[4] = fmaf(w1, xb.x, a1[4]); a1[5] = fmaf(w1, xb.y, a1[5]);
            a1[6] = fmaf(w1, xb.z, a1[6]); a1[7] = fmaf(w1, xb.w, a1[7]);
        }
        unsigned int u0[4], u1[4];
#pragma unroll
        for (int i = 0; i < 4; ++i) {
            u0[i] = (unsigned int)f2bf_bits(a0[2 * i]) |
                    ((unsigned int)f2bf_bits(a0[2 * i + 1]) << 16);
            u1[i] = (unsigned int)f2bf_bits(a1[2 * i]) |
                    ((unsigned int)f2bf_bits(a1[2 * i + 1]) << 16);
        }
        const int n = n0 + pxb;
        const int chunk = n >> 5;
        const int j = (o >> 1) & 1, hh = o & 1;
        char* base = (char*)Vf + (((size_t)((b << 7) | chunk)) << 11)
                   + (j << 10) + (hh << 9) + (c0 << 4);
        *(uint4*)base        = make_uint4(u0[0], u0[1], u0[2], u0[3]);
        *(uint4*)(base + 16) = make_uint4(u1[0], u1[1], u1[2], u1[3]);
    }
}

// ---------------- Kernel 2: split flash attention + tail combine ----------------
// grid (32 q-quads, 4 batch, 8 key-eighths) x 256 thr. Wave w owns local
// chunks 0..3 of keys [eighth*512 + w*128, +128). Four q-tiles (T=0..3)
// share every K/V load. Writes pnum/pden partials; the LAST of the 8
// eighth-blocks per (quad,b) combines them + W conv + pstats.
__global__ __launch_bounds__(256) void attn_part(
    const __hip_bfloat16* __restrict__ Qb, const __hip_bfloat16* __restrict__ Kf,
    const __hip_bfloat16* __restrict__ Vf,
    float* __restrict__ pnum, float* __restrict__ pden,
    const float* __restrict__ w_w, const float* __restrict__ w_b,
    float* __restrict__ out2, float2* __restrict__ pstats,
    unsigned int* __restrict__ cnt)
{
    __shared__ __align__(16) float redbuf[4][3][64][16];   // 48 KB
    __shared__ float denarr[4][3][64];                      // 3 KB
    __shared__ unsigned int lastFlag;
    const int tid = threadIdx.x, lane = tid & 63, w = tid >> 6;
    const int q = lane & 31, h = lane >> 5;
    const int b = blockIdx.y, qbase = blockIdx.x << 7, eighth = blockIdx.z;

    // Q B-frags for 4 tiles: B[k=ci][n=q] -> Qb[qbase+32T+q][ci=8h.. (+16)]
    const __hip_bfloat16* QrowA = Qb + (((size_t)(b << 12) + qbase + q) << 5);
    const bf16x8 bq1A = *(const bf16x8*)(QrowA + 8 * h);
    const bf16x8 bq2A = *(const bf16x8*)(QrowA + 16 + 8 * h);
    const bf16x8 bq1B = *(const bf16x8*)(QrowA + (32 << 5) + 8 * h);
    const bf16x8 bq2B = *(const bf16x8*)(QrowA + (32 << 5) + 16 + 8 * h);
    const bf16x8 bq1C = *(const bf16x8*)(QrowA + (64 << 5) + 8 * h);
    const bf16x8 bq2C = *(const bf16x8*)(QrowA + (64 << 5) + 16 + 8 * h);
    const bf16x8 bq1D = *(const bf16x8*)(QrowA + (96 << 5) + 8 * h);
    const bf16x8 bq2D = *(const bf16x8*)(QrowA + (96 << 5) + 16 + 8 * h);

    // wave's 4 chunks start at global chunk (b*128 + eighth*16 + w*4)
    const char* Kc = (const char*)Kf +
        ((size_t)((b << 7) | (eighth << 4) | (w << 2)) << 11) + (lane << 4);
    const char* Vc = (const char*)Vf +
        ((size_t)((b << 7) | (eighth << 4) | (w << 2)) << 11) + (lane << 4);
#define LDK1(c) (*(const bf16x8*)(Kc + ((c) << 11)))
#define LDK2(c) (*(const bf16x8*)(Kc + ((c) << 11) + 1024))
#define LDV1(c) (*(const bf16x8*)(Vc + ((c) << 11)))
#define LDV2(c) (*(const bf16x8*)(Vc + ((c) << 11) + 1024))

    f32x16 accA, accB, accC, accD;
#pragma unroll
    for (int r = 0; r < 16; ++r) { accA[r]=0.f; accB[r]=0.f; accC[r]=0.f; accD[r]=0.f; }
    const f32x16 z16 = accA;
    float denA = 0.f, denB = 0.f, denC = 0.f, denD = 0.f;

    bf16x8 a1c = LDK1(0), a2c = LDK2(0);
    bf16x8 vb1 = LDV1(0), vb2 = LDV2(0);
    bf16x8 a1n = LDK1(1), a2n = LDK2(1);
    bf16x8 vn1 = LDV1(1), vn2 = LDV2(1);
    bf16x8 apA1, apA2, apB1, apB2, apC1, apC2, apD1, apD2, vp1, vp2;

    // ---- chunk 0: S phase only, all tiles ----
    {
        f32x16 s = __builtin_amdgcn_mfma_f32_32x32x16_bf16(a1c, bq1A, z16, 0, 0, 0);
        s = __builtin_amdgcn_mfma_f32_32x32x16_bf16(a2c, bq2A, s, 0, 0, 0);
        softmax_pack(s, denA, apA1, apA2);
        s = __builtin_amdgcn_mfma_f32_32x32x16_bf16(a1c, bq1B, z16, 0, 0, 0);
        s = __builtin_amdgcn_mfma_f32_32x32x16_bf16(a2c, bq2B, s, 0, 0, 0);
        softmax_pack(s, denB, apB1, apB2);
        s = __builtin_amdgcn_mfma_f32_32x32x16_bf16(a1c, bq1C, z16, 0, 0, 0);
        s = __builtin_amdgcn_mfma_f32_32x32x16_bf16(a2c, bq2C, s, 0, 0, 0);
        softmax_pack(s, denC, apC1, apC2);
        s = __builtin_amdgcn_mfma_f32_32x32x16_bf16(a1c, bq1D, z16, 0, 0, 0);
        s = __builtin_amdgcn_mfma_f32_32x32x16_bf16(a2c, bq2D, s, 0, 0, 0);
        softmax_pack(s, denD, apD1, apD2);
    }

#pragma unroll
    for (int ch = 1; ch < 4; ++ch) {
        const int kn = (ch + 1) & 3;   // last iter wraps in-range
        vp1 = vb1; vp2 = vb2;          // V(ch-1) for this iter's PV
        vb1 = vn1; vb2 = vn2;          // V(ch)
        a1c = a1n; a2c = a2n;          // K(ch)
        a1n = LDK1(kn); a2n = LDK2(kn);
        vn1 = LDV1(kn); vn2 = LDV2(kn);

        // PV of chunk ch-1 (ap packed last iteration, shared V frags)
        accA = __builtin_amdgcn_mfma_f32_32x32x16_bf16(apA1, vp1, accA, 0, 0, 0);
        accA = __builtin_amdgcn_mfma_f32_32x32x16_bf16(apA2, vp2, accA, 0, 0, 0);
        accB = __builtin_amdgcn_mfma_f32_32x32x16_bf16(apB1, vp1, accB, 0, 0, 0);
        accB = __builtin_amdgcn_mfma_f32_32x32x16_bf16(apB2, vp2, accB, 0, 0, 0);
        accC = __builtin_amdgcn_mfma_f32_32x32x16_bf16(apC1, vp1, accC, 0, 0, 0);
        accC = __builtin_amdgcn_mfma_f32_32x32x16_bf16(apC2, vp2, accC, 0, 0, 0);
        accD = __builtin_amdgcn_mfma_f32_32x32x16_bf16(apD1, vp1, accD, 0, 0, 0);
        accD = __builtin_amdgcn_mfma_f32_32x32x16_bf16(apD2, vp2, accD, 0, 0, 0);

        // S of chunk ch, all tiles (shared K frags), softmax immediately
        f32x16 s = __builtin_amdgcn_mfma_f32_32x32x16_bf16(a1c, bq1A, z16, 0, 0, 0);
        s = __builtin_amdgcn_mfma_f32_32x32x16_bf16(a2c, bq2A, s, 0, 0, 0);
        softmax_pack(s, denA, apA1, apA2);
        s = __builtin_amdgcn_mfma_f32_32x32x16_bf16(a1c, bq1B, z16, 0, 0, 0);
        s = __builtin_amdgcn_mfma_f32_32x32x16_bf16(a2c, bq2B, s, 0, 0, 0);
        softmax_pack(s, denB, apB1, apB2);
        s = __builtin_amdgcn_mfma_f32_32x32x16_bf16(a1c, bq1C, z16, 0, 0, 0);
        s = __builtin_amdgcn_mfma_f32_32x32x16_bf16(a2c, bq2C, s, 0, 0, 0);
        softmax_pack(s, denC, apC1, apC2);
        s = __builtin_amdgcn_mfma_f32_32x32x16_bf16(a1c, bq1D, z16, 0, 0, 0);
        s = __builtin_amdgcn_mfma_f32_32x32x16_bf16(a2c, bq2D, s, 0, 0, 0);
        softmax_pack(s, denD, apD1, apD2);
    }
    // tail: PV of chunk 3 (V(3) sits in vb1/vb2 after last rotation)
    accA = __builtin_amdgcn_mfma_f32_32x32x16_bf16(apA1, vb1, accA, 0, 0, 0);
    accA = __builtin_amdgcn_mfma_f32_32x32x16_bf16(apA2, vb2, accA, 0, 0, 0);
    accB = __builtin_amdgcn_mfma_f32_32x32x16_bf16(apB1, vb1, accB, 0, 0, 0);
    accB = __builtin_amdgcn_mfma_f32_32x32x16_bf16(apB2, vb2, accB, 0, 0, 0);
    accC = __builtin_amdgcn_mfma_f32_32x32x16_bf16(apC1, vb1, accC, 0, 0, 0);
    accC = __builtin_amdgcn_mfma_f32_32x32x16_bf16(apC2, vb2, accC, 0, 0, 0);
    accD = __builtin_amdgcn_mfma_f32_32x32x16_bf16(apD1, vb1, accD, 0, 0, 0);
    accD = __builtin_amdgcn_mfma_f32_32x32x16_bf16(apD2, vb2, accD, 0, 0, 0);
#undef LDK1
#undef LDK2
#undef LDV1
#undef LDV2

    // den(lane) covers query q over this lane's 16 keys/chunk; other half:
    denA += __shfl_xor(denA, 32);
    denB += __shfl_xor(denB, 32);
    denC += __shfl_xor(denC, 32);
    denD += __shfl_xor(denD, 32);

    // cross-wave combine, single barrier round
    if (w) {
        float d[4] = {denA, denB, denC, denD};
        const f32x16* av[4] = {&accA, &accB, &accC, &accD};
#pragma unroll
        for (int T = 0; T < 4; ++T) {
            float* rb = &redbuf[T][w - 1][lane][0];
            f32x4* rb4 = (f32x4*)rb;
            const f32x16& a = *av[T];
#pragma unroll
            for (int p = 0; p < 4; ++p) {
                f32x4 t = {a[4*p], a[4*p+1], a[4*p+2], a[4*p+3]};
                rb4[p] = t;
            }
            denarr[T][w - 1][lane] = d[T];
        }
    }
    __syncthreads();
    if (w == 0) {
        const int tbase = (((eighth << 2) | b) << 7) | (blockIdx.x << 2);
        float d[4] = {denA, denB, denC, denD};
        f32x16* av[4] = {&accA, &accB, &accC, &accD};
#pragma unroll
        for (int T = 0; T < 4; ++T) {
            f32x16& a = *av[T];
#pragma unroll
            for (int ww = 0; ww < 3; ++ww) {
                const float* rb = &redbuf[T][ww][lane][0];
                const f32x4* rb4 = (const f32x4*)rb;
#pragma unroll
                for (int p = 0; p < 4; ++p) {
                    f32x4 t = rb4[p];
                    a[4*p] += t[0]; a[4*p+1] += t[1];
                    a[4*p+2] += t[2]; a[4*p+3] += t[3];
                }
                d[T] += denarr[T][ww][lane];
            }
            // O^T C-layout: row(query)=(r&3)+8*(r>>2)+4h, col(ci)=q
            float* pn = pnum + ((size_t)(tbase + T) << 10);
#pragma unroll
            for (int r = 0; r < 16; ++r) {
                int qr = (r & 3) + 8 * (r >> 2) + 4 * h;
                pn[(qr << 5) + q] = a[r];
            }
            if (h == 0) pden[((tbase + T) << 5) + q] = d[T];
        }
    }

    // ---- release: signal this eighth done; last block combines ----
    __threadfence();                 // flush pnum/pden (wave 0's stores)
    __syncthreads();
    if (tid == 0)
        lastFlag = (atomicAdd(&cnt[(b << 5) | blockIdx.x], 1u) == 7u);
    __syncthreads();
    if (!lastFlag) return;
    __threadfence();                 // acquire: other blocks' partials visible

    // ---- combine 8 eighths for 4 subtiles + W conv + pstats ----
    float (*obuf)[32][36] = (float (*)[32][36])redbuf;   // reuse 18.4KB of redbuf
#pragma unroll
    for (int T = 0; T < 4; ++T) {
        const int qtile = (blockIdx.x << 2) | T;
#pragma unroll
        for (int k = 0; k < 4; ++k) {
            int e = tid + (k << 8);
            int qr = e >> 5;
            float num = 0.f, den = 0.f;
#pragma unroll
            for (int E = 0; E < 8; ++E) {
                int tile = (((E << 2) | b) << 7) | qtile;
                num += pnum[((size_t)tile << 10) + e];
                den += pden[(tile << 5) + qr];
            }
            obuf[T][qr][e & 31] = num * (1.0f / den);
        }
    }
    __syncthreads();

    const int qq = tid & 31, cog = tid >> 5;   // 8 co per thread
#pragma unroll
    for (int T = 0; T < 4; ++T) {
        const int qtile = (blockIdx.x << 2) | T;
        float ov[32];
        const float4* orow = (const float4*)&obuf[T][qq][0];
#pragma unroll
        for (int k4 = 0; k4 < 8; ++k4) {
            float4 t = orow[k4];
            ov[4*k4] = t.x; ov[4*k4+1] = t.y; ov[4*k4+2] = t.z; ov[4*k4+3] = t.w;
        }
        float* dstbase = out2 + (((size_t)(b << 6)) << 12) + (qtile << 5) + qq;
        const int tileidx = (b << 7) | qtile;   // 0..511
#pragma unroll
        for (int kk = 0; kk < 8; ++kk) {
            int co = (kk << 3) | cog;
            const float4* wr = (const float4*)&w_w[co << 5];
            float acc2 = w_b[co];
#pragma unroll
            for (int k4 = 0; k4 < 8; ++k4) {
                float4 t = wr[k4];
                acc2 = fmaf(t.x, ov[4*k4],   acc2);
                acc2 = fmaf(t.y, ov[4*k4+1], acc2);
                acc2 = fmaf(t.z, ov[4*k4+2], acc2);
                acc2 = fmaf(t.w, ov[4*k4+3], acc2);
            }
            dstbase[(size_t)co << 12] = acc2;
            // per-co partial sums over the 32 queries (32-lane half owns one co)
            float s1 = acc2, s2 = acc2 * acc2;
#pragma unroll
            for (int m = 1; m < 32; m <<= 1) {
                s1 += __shfl_xor(s1, m);
                s2 += __shfl_xor(s2, m);
            }
            if (qq == 0) pstats[(co << 9) | tileidx] = make_float2(s1, s2);
        }
    }
}

// ---------------- Kernel 3: BN (reduce partials) + bilinear + residual --------
__global__ __launch_bounds__(256) void up_kernel(
    const float* __restrict__ out2, const float2* __restrict__ pstats,
    const float* __restrict__ gamma, const float* __restrict__ beta,
    const float* __restrict__ mainf, float* __restrict__ out)
{
    int gid = blockIdx.x * 256 + threadIdx.x;   // < 4*64*128*32
    int j4 = (gid & 31) << 2;
    int i  = (gid >> 5) & 127;
    int co = (gid >> 12) & 63;            // uniform within a block
    int b  = gid >> 18;
    int t  = threadIdx.x;

    // reduce 512 per-tile partials for this co (L2-broadcast, ~4 KB)
    __shared__ float rs[256], rs2[256];
    {
        float2 p0 = pstats[(co << 9) | t];
        float2 p1 = pstats[(co << 9) | (t + 256)];
        rs[t] = p0.x + p1.x; rs2[t] = p0.y + p1.y;
    }
    __syncthreads();
    for (int off = 128; off > 0; off >>= 1) {
        if (t < off) { rs[t] += rs[t + off]; rs2[t] += rs2[t + off]; }
        __syncthreads();
    }
    float sm = rs[0], sq = rs2[0];

    float mean = sm * (1.0f / 16384.0f);
    float var  = sq * (1.0f / 16384.0f) - mean * mean;
    float inv  = rsqrtf(var + 1e-5f);
    float scale = gamma[co] * inv;
    float shift = beta[co] - mean * scale;

    int ih = i >> 1;
    int k0, k1; float wi;
    if (i & 1)       { k0 = ih;     k1 = (ih < 63) ? ih + 1 : 63; wi = 0.25f; }
    else if (ih == 0){ k0 = 0;      k1 = 0;                       wi = 0.0f;  }
    else             { k0 = ih - 1; k1 = ih;                      wi = 0.75f; }

    const float* p0r = out2 + ((size_t)((b << 6) | co) << 12) + (k0 << 6);
    const float* p1r = out2 + ((size_t)((b << 6) | co) << 12) + (k1 << 6);

    float res[4];
#pragma unroll
    for (int jj = 0; jj < 4; ++jj) {
        int j = j4 | jj;
        int il = j >> 1;
        int l0, l1; float wj;
        if (j & 1)       { l0 = il;     l1 = (il < 63) ? il + 1 : 63; wj = 0.25f; }
        else if (il == 0){ l0 = 0;      l1 = 0;                       wj = 0.0f;  }
        else             { l0 = il - 1; l1 = il;                      wj = 0.75f; }
        float v00 = p0r[l0], v01 = p0r[l1];
        float v10 = p1r[l0], v11 = p1r[l1];
        float top = v00 + wj * (v01 - v00);
        float bot = v10 + wj * (v11 - v10);
        float v = top + wi * (bot - top);
        res[jj] = fmaf(v, scale, shift);
    }
    size_t idx = (((size_t)((b << 6) | co)) << 14) + (i << 7) + j4;
    float4 m4 = *(const float4*)(mainf + idx);
    *(float4*)(out + idx) = make_float4(res[0] + m4.x, res[1] + m4.y,
                                        res[2] + m4.z, res[3] + m4.w);
}

extern "C" void kernel_launch(void* const* d_in, const int* in_sizes, int n_in,
                              void* d_out, int out_size, void* d_ws, size_t ws_size,
                              hipStream_t stream)
{
    const float* mainf = (const float*)d_in[0];
    const float* cross = (const float*)d_in[1];
    const float* g_w   = (const float*)d_in[2];
    const float* g_b   = (const float*)d_in[3];
    const float* th_w  = (const float*)d_in[4];
    const float* th_b  = (const float*)d_in[5];
    const float* ph_w  = (const float*)d_in[6];
    const float* ph_b  = (const float*)d_in[7];
    const float* w_w   = (const float*)d_in[8];
    const float* w_b   = (const float*)d_in[9];
    const float* gamma = (const float*)d_in[10];
    const float* beta  = (const float*)d_in[11];
    float* out = (float*)d_out;

    __hip_bfloat16* Qb = (__hip_bfloat16*)d_ws;     // 4*4096*32
    __hip_bfloat16* Kf = Qb + 524288;               // frag-major, 1MB
    __hip_bfloat16* Vf = Kf + 524288;               // frag-major, 1MB
    float* out2   = (float*)(Vf + 524288);          // 4*64*4096
    float* pnum   = out2 + 1048576;                 // 4096 tiles x 1024
    float* pden   = pnum + 4194304;                 // 4096 tiles x 32
    float2* pstats = (float2*)(pden + 131072);      // 64 co x 512 tiles
    unsigned int* cnt = (unsigned int*)(pstats + 32768);  // 128 counters

    qkv_kernel<<<384, 256, 0, stream>>>(cross, mainf, g_w, g_b, th_w, th_b,
                                        ph_w, ph_b, Qb, Kf, Vf, cnt);
    attn_part<<<dim3(32, 4, 8), 256, 0, stream>>>(Qb, Kf, Vf, pnum, pden,
                                                  w_w, w_b, out2, pstats, cnt);
    up_kernel<<<4096, 256, 0, stream>>>(out2, pstats, gamma, beta, mainf, out);
}

// Round 12
// 140.350 us; speedup vs baseline: 1.7779x; 1.7779x over previous
//
#include <hip/hip_runtime.h>
#include <hip/hip_bf16.h>

// CrossLocal: B=4, C=64, CI=32, cross 64x64 (Nc=4096), main 128x128.
// R22 = R20 exact revert (measured best: 141.2us). R21's last-block-combine
// regressed 2x: device-scope __threadfence on multi-XCD CDNA = L2
// writeback per block (~167us over 1024 blocks). LESSON (with R15's
// contended-atomic collapse): hot-path cross-block coherence is ~100-200us
// at this scale; producer->consumer must cross kernel boundaries (~2us).
// Structure: 8-way key split (grid 32x4x8, 3 blocks/CU via 51KB LDS),
// fragment-major K/V (R18), 4 q-tiles/block sharing every load (R17),
// coalesced qkv V-writes (R19a), no atomics / no fences anywhere.
// ws: Qb[bf16 1MB] Kf[1MB] Vf[1MB] out2[f32 4MB] pnum[f32 16MB]
//     pden[f32 512KB] pstats[f32x2 64x512]

typedef __attribute__((ext_vector_type(8))) short bf16x8;
typedef __attribute__((ext_vector_type(4))) float f32x4;
typedef __attribute__((ext_vector_type(16))) float f32x16;

#define LOG2E 1.4426950408889634f

static __device__ __forceinline__ unsigned short f2bf_bits(float x) {
    __hip_bfloat16 h = __float2bfloat16(x);
    return *(unsigned short*)&h;
}
static __device__ __forceinline__ unsigned int pk2bf(float a, float b) {
    __hip_bfloat162 h = __float22bfloat162_rn(make_float2(a, b));
    return *(unsigned int*)&h;
}

// exp2 all 16 S entries, accumulate denominator, pack to two bf16x8 A-frags.
static __device__ __forceinline__ void softmax_pack(
    const f32x16& s, float& den, bf16x8& ap1, bf16x8& ap2)
{
    float e[16];
#pragma unroll
    for (int r = 0; r < 16; ++r) e[r] = __builtin_amdgcn_exp2f(s[r]);
    den += (((e[0]+e[1])+(e[2]+e[3])) + ((e[4]+e[5])+(e[6]+e[7])))
         + (((e[8]+e[9])+(e[10]+e[11])) + ((e[12]+e[13])+(e[14]+e[15])));
    uint4 t1 = make_uint4(pk2bf(e[0],e[1]), pk2bf(e[2],e[3]),
                          pk2bf(e[4],e[5]), pk2bf(e[6],e[7]));
    uint4 t2 = make_uint4(pk2bf(e[8],e[9]), pk2bf(e[10],e[11]),
                          pk2bf(e[12],e[13]), pk2bf(e[14],e[15]));
    ap1 = *(bf16x8*)&t1; ap2 = *(bf16x8*)&t2;
}

// ---------------- Kernel 1: Q,K,V prep (coalesced fragment-major writes) ------
__global__ __launch_bounds__(256) void qkv_kernel(
    const float* __restrict__ cross, const float* __restrict__ mainf,
    const float* __restrict__ g_w,  const float* __restrict__ g_b,
    const float* __restrict__ th_w, const float* __restrict__ th_b,
    const float* __restrict__ ph_w, const float* __restrict__ ph_b,
    __hip_bfloat16* __restrict__ Qb, __hip_bfloat16* __restrict__ Kf,
    __hip_bfloat16* __restrict__ Vf)
{
    __shared__ __align__(16) float xs[64][128];   // 32 KB
    const int kind = blockIdx.x >> 7;        // 0=Q,1=K,2=V
    const int sub  = blockIdx.x & 127;
    const int b    = sub >> 5;
    const int n0   = (sub & 31) << 7;        // 128 pixels per block
    const int tid  = threadIdx.x;
    const float* w  = (kind == 0) ? g_w : (kind == 1) ? th_w : ph_w;
    const float* bs = (kind == 0) ? g_b : (kind == 1) ? th_b : ph_b;

    if (kind < 2) {
        const float* src = cross + (((size_t)(b * 64)) << 12) + n0;
        const int jr = (tid & 31) << 2, c0 = tid >> 5;
#pragma unroll
        for (int it = 0; it < 8; ++it) {
            int c = (it << 3) | c0;
            *(float4*)&xs[c][jr] = *(const float4*)(src + ((size_t)c << 12) + jr);
        }
    } else {
        const int px = tid & 127, chh = tid >> 7;
        const int n = n0 + px;
        const int i2 = (n >> 6) << 1, j2 = (n & 63) << 1;
        const float* src = mainf + (((size_t)(b * 64)) << 14) + i2 * 128 + j2;
#pragma unroll 4
        for (int cc = 0; cc < 32; ++cc) {
            int c = (chh << 5) | cc;
            const float2 a = *(const float2*)(src + ((size_t)c << 14));
            const float2 d = *(const float2*)(src + ((size_t)c << 14) + 128);
            xs[c][px] = 0.25f * ((a.x + a.y) + (d.x + d.y));
        }
    }
    __syncthreads();

    if (kind < 2) {
        const int px = tid & 127, cih = tid >> 7, ci0 = cih << 4;
        float acc[16];
#pragma unroll
        for (int j = 0; j < 16; ++j) acc[j] = bs[ci0 + j];
#pragma unroll 4
        for (int c = 0; c < 64; ++c) {
            float x = xs[c][px];
#pragma unroll
            for (int j = 0; j < 16; ++j)
                acc[j] = fmaf(w[((ci0 + j) << 6) + c], x, acc[j]);
        }
        const int n = n0 + px;
        const int chunk = n >> 5, kk = n & 31;
        if (kind == 0) {
#pragma unroll
            for (int j = 0; j < 16; ++j) acc[j] *= LOG2E;
            unsigned int u[8];
#pragma unroll
            for (int i = 0; i < 8; ++i)
                u[i] = (unsigned int)f2bf_bits(acc[2 * i]) |
                       ((unsigned int)f2bf_bits(acc[2 * i + 1]) << 16);
            uint4* d4 = (uint4*)(Qb + (size_t)((b << 12) + n) * 32 + ci0);
            d4[0] = make_uint4(u[0], u[1], u[2], u[3]);
            d4[1] = make_uint4(u[4], u[5], u[6], u[7]);
        } else {
            // K fragment-major: frag(j=cih, lane=h'*32+sig(kk)) <- ci0+8h'..+7
            unsigned int u[8];
#pragma unroll
            for (int i = 0; i < 8; ++i)
                u[i] = (unsigned int)f2bf_bits(acc[2 * i]) |
                       ((unsigned int)f2bf_bits(acc[2 * i + 1]) << 16);
            const int q = (kk & ~12) | ((kk & 4) << 1) | ((kk & 8) >> 1);  // sigma
            char* base = (char*)Kf + ((((size_t)(b << 7) | chunk) << 11) | (cih << 10));
            *(uint4*)(base + (q << 4))          = make_uint4(u[0], u[1], u[2], u[3]);
            *(uint4*)(base + ((32 + q) << 4))   = make_uint4(u[4], u[5], u[6], u[7]);
        }
    } else {
        // V: thread = (ci pair, key octet) -> 2 coalesced 16B fragment stores
        const int cip = tid & 15, o = tid >> 4;     // o in 0..15
        const int c0 = cip << 1;
        const int pxb = o << 3;
        float a0[8], a1[8];
        const float b0 = bs[c0], b1 = bs[c0 + 1];
#pragma unroll
        for (int i = 0; i < 8; ++i) { a0[i] = b0; a1[i] = b1; }
#pragma unroll 4
        for (int c = 0; c < 64; ++c) {
            const float w0 = w[(c0 << 6) + c], w1 = w[((c0 + 1) << 6) + c];
            const float4 xa = *(const float4*)&xs[c][pxb];
            const float4 xb = *(const float4*)&xs[c][pxb + 4];
            a0[0] = fmaf(w0, xa.x, a0[0]); a0[1] = fmaf(w0, xa.y, a0[1]);
            a0[2] = fmaf(w0, xa.z, a0[2]); a0[3] = fmaf(w0, xa.w, a0[3]);
            a0[4] = fmaf(w0, xb.x, a0[4]); a0[5] = fmaf(w0, xb.y, a0[5]);
            a0[6] = fmaf(w0, xb.z, a0[6]); a0[7] = fmaf(w0, xb.w, a0[7]);
            a1[0] = fmaf(w1, xa.x, a1[0]); a1[1] = fmaf(w1, xa.y, a1[1]);
            a1[2] = fmaf(w1, xa.z, a1[2]); a1[3] = fmaf(w1, xa.w, a1[3]);
            a1[4] = fmaf(w1, xb.x, a1[4]); a1[5] = fmaf(w1, xb.y, a1[5]);
            a1[6] = fmaf(w1, xb.z, a1[6]); a1[7] = fmaf(w1, xb.w, a1[7]);
        }
        unsigned int u0[4], u1[4];
#pragma unroll
        for (int i = 0; i < 4; ++i) {
            u0[i] = (unsigned int)f2bf_bits(a0[2 * i]) |
                    ((unsigned int)f2bf_bits(a0[2 * i + 1]) << 16);
            u1[i] = (unsigned int)f2bf_bits(a1[2 * i]) |
                    ((unsigned int)f2bf_bits(a1[2 * i + 1]) << 16);
        }
        const int n = n0 + pxb;
        const int chunk = n >> 5;
        const int j = (o >> 1) & 1, hh = o & 1;
        char* base = (char*)Vf + (((size_t)((b << 7) | chunk)) << 11)
                   + (j << 10) + (hh << 9) + (c0 << 4);
        *(uint4*)base        = make_uint4(u0[0], u0[1], u0[2], u0[3]);
        *(uint4*)(base + 16) = make_uint4(u1[0], u1[1], u1[2], u1[3]);
    }
}

// ---------------- Kernel 2: split flash attention, 128-q blocks ----------------
// grid (32 q-quads, 4 batch, 8 key-eighths) x 256 thr. Wave w owns local
// chunks 0..3 of keys [eighth*512 + w*128, +128). Four q-tiles (T=0..3 at
// qbase+32T) share every K/V load; all loads coalesced lane*16 bursts.
// Writes pnum[tile][32q][32ci], pden[tile][32q];
// tile = ((eighth*4+b)<<7) | (blockIdx.x*4+T).
__global__ __launch_bounds__(256) void attn_part(
    const __hip_bfloat16* __restrict__ Qb, const __hip_bfloat16* __restrict__ Kf,
    const __hip_bfloat16* __restrict__ Vf,
    float* __restrict__ pnum, float* __restrict__ pden)
{
    __shared__ __align__(16) float redbuf[4][3][64][16];   // 48 KB, rows 16B-aligned
    __shared__ float denarr[4][3][64];                      // 3 KB
    const int tid = threadIdx.x, lane = tid & 63, w = tid >> 6;
    const int q = lane & 31, h = lane >> 5;
    const int b = blockIdx.y, qbase = blockIdx.x << 7, eighth = blockIdx.z;

    // Q B-frags for 4 tiles: B[k=ci][n=q] -> Qb[qbase+32T+q][ci=8h.. (+16)]
    const __hip_bfloat16* QrowA = Qb + (((size_t)(b << 12) + qbase + q) << 5);
    const bf16x8 bq1A = *(const bf16x8*)(QrowA + 8 * h);
    const bf16x8 bq2A = *(const bf16x8*)(QrowA + 16 + 8 * h);
    const bf16x8 bq1B = *(const bf16x8*)(QrowA + (32 << 5) + 8 * h);
    const bf16x8 bq2B = *(const bf16x8*)(QrowA + (32 << 5) + 16 + 8 * h);
    const bf16x8 bq1C = *(const bf16x8*)(QrowA + (64 << 5) + 8 * h);
    const bf16x8 bq2C = *(const bf16x8*)(QrowA + (64 << 5) + 16 + 8 * h);
    const bf16x8 bq1D = *(const bf16x8*)(QrowA + (96 << 5) + 8 * h);
    const bf16x8 bq2D = *(const bf16x8*)(QrowA + (96 << 5) + 16 + 8 * h);

    // wave's 4 chunks start at global chunk (b*128 + eighth*16 + w*4)
    const char* Kc = (const char*)Kf +
        ((size_t)((b << 7) | (eighth << 4) | (w << 2)) << 11) + (lane << 4);
    const char* Vc = (const char*)Vf +
        ((size_t)((b << 7) | (eighth << 4) | (w << 2)) << 11) + (lane << 4);
#define LDK1(c) (*(const bf16x8*)(Kc + ((c) << 11)))
#define LDK2(c) (*(const bf16x8*)(Kc + ((c) << 11) + 1024))
#define LDV1(c) (*(const bf16x8*)(Vc + ((c) << 11)))
#define LDV2(c) (*(const bf16x8*)(Vc + ((c) << 11) + 1024))

    f32x16 accA, accB, accC, accD;
#pragma unroll
    for (int r = 0; r < 16; ++r) { accA[r]=0.f; accB[r]=0.f; accC[r]=0.f; accD[r]=0.f; }
    const f32x16 z16 = accA;
    float denA = 0.f, denB = 0.f, denC = 0.f, denD = 0.f;

    bf16x8 a1c = LDK1(0), a2c = LDK2(0);
    bf16x8 vb1 = LDV1(0), vb2 = LDV2(0);
    bf16x8 a1n = LDK1(1), a2n = LDK2(1);
    bf16x8 vn1 = LDV1(1), vn2 = LDV2(1);
    bf16x8 apA1, apA2, apB1, apB2, apC1, apC2, apD1, apD2, vp1, vp2;

    // ---- chunk 0: S phase only, all tiles ----
    {
        f32x16 s = __builtin_amdgcn_mfma_f32_32x32x16_bf16(a1c, bq1A, z16, 0, 0, 0);
        s = __builtin_amdgcn_mfma_f32_32x32x16_bf16(a2c, bq2A, s, 0, 0, 0);
        softmax_pack(s, denA, apA1, apA2);
        s = __builtin_amdgcn_mfma_f32_32x32x16_bf16(a1c, bq1B, z16, 0, 0, 0);
        s = __builtin_amdgcn_mfma_f32_32x32x16_bf16(a2c, bq2B, s, 0, 0, 0);
        softmax_pack(s, denB, apB1, apB2);
        s = __builtin_amdgcn_mfma_f32_32x32x16_bf16(a1c, bq1C, z16, 0, 0, 0);
        s = __builtin_amdgcn_mfma_f32_32x32x16_bf16(a2c, bq2C, s, 0, 0, 0);
        softmax_pack(s, denC, apC1, apC2);
        s = __builtin_amdgcn_mfma_f32_32x32x16_bf16(a1c, bq1D, z16, 0, 0, 0);
        s = __builtin_amdgcn_mfma_f32_32x32x16_bf16(a2c, bq2D, s, 0, 0, 0);
        softmax_pack(s, denD, apD1, apD2);
    }

#pragma unroll
    for (int ch = 1; ch < 4; ++ch) {
        const int kn = (ch + 1) & 3;   // last iter wraps in-range
        vp1 = vb1; vp2 = vb2;          // V(ch-1) for this iter's PV
        vb1 = vn1; vb2 = vn2;          // V(ch)
        a1c = a1n; a2c = a2n;          // K(ch)
        a1n = LDK1(kn); a2n = LDK2(kn);
        vn1 = LDV1(kn); vn2 = LDV2(kn);

        // PV of chunk ch-1 (ap packed last iteration, shared V frags)
        accA = __builtin_amdgcn_mfma_f32_32x32x16_bf16(apA1, vp1, accA, 0, 0, 0);
        accA = __builtin_amdgcn_mfma_f32_32x32x16_bf16(apA2, vp2, accA, 0, 0, 0);
        accB = __builtin_amdgcn_mfma_f32_32x32x16_bf16(apB1, vp1, accB, 0, 0, 0);
        accB = __builtin_amdgcn_mfma_f32_32x32x16_bf16(apB2, vp2, accB, 0, 0, 0);
        accC = __builtin_amdgcn_mfma_f32_32x32x16_bf16(apC1, vp1, accC, 0, 0, 0);
        accC = __builtin_amdgcn_mfma_f32_32x32x16_bf16(apC2, vp2, accC, 0, 0, 0);
        accD = __builtin_amdgcn_mfma_f32_32x32x16_bf16(apD1, vp1, accD, 0, 0, 0);
        accD = __builtin_amdgcn_mfma_f32_32x32x16_bf16(apD2, vp2, accD, 0, 0, 0);

        // S of chunk ch, all tiles (shared K frags), softmax immediately
        f32x16 s = __builtin_amdgcn_mfma_f32_32x32x16_bf16(a1c, bq1A, z16, 0, 0, 0);
        s = __builtin_amdgcn_mfma_f32_32x32x16_bf16(a2c, bq2A, s, 0, 0, 0);
        softmax_pack(s, denA, apA1, apA2);
        s = __builtin_amdgcn_mfma_f32_32x32x16_bf16(a1c, bq1B, z16, 0, 0, 0);
        s = __builtin_amdgcn_mfma_f32_32x32x16_bf16(a2c, bq2B, s, 0, 0, 0);
        softmax_pack(s, denB, apB1, apB2);
        s = __builtin_amdgcn_mfma_f32_32x32x16_bf16(a1c, bq1C, z16, 0, 0, 0);
        s = __builtin_amdgcn_mfma_f32_32x32x16_bf16(a2c, bq2C, s, 0, 0, 0);
        softmax_pack(s, denC, apC1, apC2);
        s = __builtin_amdgcn_mfma_f32_32x32x16_bf16(a1c, bq1D, z16, 0, 0, 0);
        s = __builtin_amdgcn_mfma_f32_32x32x16_bf16(a2c, bq2D, s, 0, 0, 0);
        softmax_pack(s, denD, apD1, apD2);
    }
    // tail: PV of chunk 3 (V(3) sits in vb1/vb2 after last rotation)
    accA = __builtin_amdgcn_mfma_f32_32x32x16_bf16(apA1, vb1, accA, 0, 0, 0);
    accA = __builtin_amdgcn_mfma_f32_32x32x16_bf16(apA2, vb2, accA, 0, 0, 0);
    accB = __builtin_amdgcn_mfma_f32_32x32x16_bf16(apB1, vb1, accB, 0, 0, 0);
    accB = __builtin_amdgcn_mfma_f32_32x32x16_bf16(apB2, vb2, accB, 0, 0, 0);
    accC = __builtin_amdgcn_mfma_f32_32x32x16_bf16(apC1, vb1, accC, 0, 0, 0);
    accC = __builtin_amdgcn_mfma_f32_32x32x16_bf16(apC2, vb2, accC, 0, 0, 0);
    accD = __builtin_amdgcn_mfma_f32_32x32x16_bf16(apD1, vb1, accD, 0, 0, 0);
    accD = __builtin_amdgcn_mfma_f32_32x32x16_bf16(apD2, vb2, accD, 0, 0, 0);
#undef LDK1
#undef LDK2
#undef LDV1
#undef LDV2

    // den(lane) covers query q over this lane's 16 keys/chunk; other half:
    denA += __shfl_xor(denA, 32);
    denB += __shfl_xor(denB, 32);
    denC += __shfl_xor(denC, 32);
    denD += __shfl_xor(denD, 32);

    // cross-wave combine, single barrier round
    if (w) {
        float d[4] = {denA, denB, denC, denD};
        const f32x16* av[4] = {&accA, &accB, &accC, &accD};
#pragma unroll
        for (int T = 0; T < 4; ++T) {
            float* rb = &redbuf[T][w - 1][lane][0];
            f32x4* rb4 = (f32x4*)rb;
            const f32x16& a = *av[T];
#pragma unroll
            for (int p = 0; p < 4; ++p) {
                f32x4 t = {a[4*p], a[4*p+1], a[4*p+2], a[4*p+3]};
                rb4[p] = t;
            }
            denarr[T][w - 1][lane] = d[T];
        }
    }
    __syncthreads();
    if (w == 0) {
        const int tbase = (((eighth << 2) | b) << 7) | (blockIdx.x << 2);
        float d[4] = {denA, denB, denC, denD};
        f32x16* av[4] = {&accA, &accB, &accC, &accD};
#pragma unroll
        for (int T = 0; T < 4; ++T) {
            f32x16& a = *av[T];
#pragma unroll
            for (int ww = 0; ww < 3; ++ww) {
                const float* rb = &redbuf[T][ww][lane][0];
                const f32x4* rb4 = (const f32x4*)rb;
#pragma unroll
                for (int p = 0; p < 4; ++p) {
                    f32x4 t = rb4[p];
                    a[4*p] += t[0]; a[4*p+1] += t[1];
                    a[4*p+2] += t[2]; a[4*p+3] += t[3];
                }
                d[T] += denarr[T][ww][lane];
            }
            // O^T C-layout: row(query)=(r&3)+8*(r>>2)+4h, col(ci)=q
            float* pn = pnum + ((size_t)(tbase + T) << 10);
#pragma unroll
            for (int r = 0; r < 16; ++r) {
                int qr = (r & 3) + 8 * (r >> 2) + 4 * h;
                pn[(qr << 5) + q] = a[r];
            }
            if (h == 0) pden[((tbase + T) << 5) + q] = d[T];
        }
    }
}

// ---------------- Kernel 2b: combine eighths + W conv + BN partials ----------
// grid (128 qtiles, 4 batch) x 256 thr. No atomics: per-(co,tile) partial
// stats written to pstats[(co<<9)|tileidx] (float2 sum,sumsq).
__global__ __launch_bounds__(256) void attn_combine(
    const float* __restrict__ pnum, const float* __restrict__ pden,
    const float* __restrict__ w_w, const float* __restrict__ w_b,
    float* __restrict__ out2, float2* __restrict__ pstats)
{
    __shared__ __align__(16) float obuf[32][36];
    const int tid = threadIdx.x;
    const int b = blockIdx.y, qbase = blockIdx.x << 5;

#pragma unroll
    for (int k = 0; k < 4; ++k) {
        int e = tid + (k << 8);
        int qr = e >> 5;
        float num = 0.f, den = 0.f;
#pragma unroll
        for (int eighth = 0; eighth < 8; ++eighth) {
            int tile = (((eighth << 2) | b) << 7) | blockIdx.x;
            num += pnum[((size_t)tile << 10) + e];
            den += pden[(tile << 5) + qr];
        }
        obuf[qr][e & 31] = num * (1.0f / den);
    }
    __syncthreads();

    // ---- fused W 1x1 conv over the 32-query tile + BN partial sums ----
    const int qq = tid & 31, cog = tid >> 5;   // 8 co per thread
    float ov[32];
    const float4* orow = (const float4*)&obuf[qq][0];
#pragma unroll
    for (int k4 = 0; k4 < 8; ++k4) {
        float4 t = orow[k4];
        ov[4*k4] = t.x; ov[4*k4+1] = t.y; ov[4*k4+2] = t.z; ov[4*k4+3] = t.w;
    }
    float* dstbase = out2 + (((size_t)(b << 6)) << 12) + qbase + qq;
    const int tileidx = (b << 7) | blockIdx.x;   // 0..511
#pragma unroll
    for (int kk = 0; kk < 8; ++kk) {
        int co = (kk << 3) | cog;
        const float4* wr = (const float4*)&w_w[co << 5];
        float acc2 = w_b[co];
#pragma unroll
        for (int k4 = 0; k4 < 8; ++k4) {
            float4 t = wr[k4];
            acc2 = fmaf(t.x, ov[4*k4],   acc2);
            acc2 = fmaf(t.y, ov[4*k4+1], acc2);
            acc2 = fmaf(t.z, ov[4*k4+2], acc2);
            acc2 = fmaf(t.w, ov[4*k4+3], acc2);
        }
        dstbase[(size_t)co << 12] = acc2;
        // per-co partial sums over the 32 queries (32-lane half owns one co)
        float s1 = acc2, s2 = acc2 * acc2;
#pragma unroll
        for (int m = 1; m < 32; m <<= 1) {
            s1 += __shfl_xor(s1, m);
            s2 += __shfl_xor(s2, m);
        }
        if (qq == 0) pstats[(co << 9) | tileidx] = make_float2(s1, s2);
    }
}

// ---------------- Kernel 3: BN (reduce partials) + bilinear + residual --------
__global__ __launch_bounds__(256) void up_kernel(
    const float* __restrict__ out2, const float2* __restrict__ pstats,
    const float* __restrict__ gamma, const float* __restrict__ beta,
    const float* __restrict__ mainf, float* __restrict__ out)
{
    int gid = blockIdx.x * 256 + threadIdx.x;   // < 4*64*128*32
    int j4 = (gid & 31) << 2;
    int i  = (gid >> 5) & 127;
    int co = (gid >> 12) & 63;            // uniform within a block
    int b  = gid >> 18;
    int t  = threadIdx.x;

    // reduce 512 per-tile partials for this co (L2-broadcast, ~4 KB)
    __shared__ float rs[256], rs2[256];
    {
        float2 p0 = pstats[(co << 9) | t];
        float2 p1 = pstats[(co << 9) | (t + 256)];
        rs[t] = p0.x + p1.x; rs2[t] = p0.y + p1.y;
    }
    __syncthreads();
    for (int off = 128; off > 0; off >>= 1) {
        if (t < off) { rs[t] += rs[t + off]; rs2[t] += rs2[t + off]; }
        __syncthreads();
    }
    float sm = rs[0], sq = rs2[0];

    float mean = sm * (1.0f / 16384.0f);
    float var  = sq * (1.0f / 16384.0f) - mean * mean;
    float inv  = rsqrtf(var + 1e-5f);
    float scale = gamma[co] * inv;
    float shift = beta[co] - mean * scale;

    int ih = i >> 1;
    int k0, k1; float wi;
    if (i & 1)       { k0 = ih;     k1 = (ih < 63) ? ih + 1 : 63; wi = 0.25f; }
    else if (ih == 0){ k0 = 0;      k1 = 0;                       wi = 0.0f;  }
    else             { k0 = ih - 1; k1 = ih;                      wi = 0.75f; }

    const float* p0r = out2 + ((size_t)((b << 6) | co) << 12) + (k0 << 6);
    const float* p1r = out2 + ((size_t)((b << 6) | co) << 12) + (k1 << 6);

    float res[4];
#pragma unroll
    for (int jj = 0; jj < 4; ++jj) {
        int j = j4 | jj;
        int il = j >> 1;
        int l0, l1; float wj;
        if (j & 1)       { l0 = il;     l1 = (il < 63) ? il + 1 : 63; wj = 0.25f; }
        else if (il == 0){ l0 = 0;      l1 = 0;                       wj = 0.0f;  }
        else             { l0 = il - 1; l1 = il;                      wj = 0.75f; }
        float v00 = p0r[l0], v01 = p0r[l1];
        float v10 = p1r[l0], v11 = p1r[l1];
        float top = v00 + wj * (v01 - v00);
        float bot = v10 + wj * (v11 - v10);
        float v = top + wi * (bot - top);
        res[jj] = fmaf(v, scale, shift);
    }
    size_t idx = (((size_t)((b << 6) | co)) << 14) + (i << 7) + j4;
    float4 m4 = *(const float4*)(mainf + idx);
    *(float4*)(out + idx) = make_float4(res[0] + m4.x, res[1] + m4.y,
                                        res[2] + m4.z, res[3] + m4.w);
}

extern "C" void kernel_launch(void* const* d_in, const int* in_sizes, int n_in,
                              void* d_out, int out_size, void* d_ws, size_t ws_size,
                              hipStream_t stream)
{
    const float* mainf = (const float*)d_in[0];
    const float* cross = (const float*)d_in[1];
    const float* g_w   = (const float*)d_in[2];
    const float* g_b   = (const float*)d_in[3];
    const float* th_w  = (const float*)d_in[4];
    const float* th_b  = (const float*)d_in[5];
    const float* ph_w  = (const float*)d_in[6];
    const float* ph_b  = (const float*)d_in[7];
    const float* w_w   = (const float*)d_in[8];
    const float* w_b   = (const float*)d_in[9];
    const float* gamma = (const float*)d_in[10];
    const float* beta  = (const float*)d_in[11];
    float* out = (float*)d_out;

    __hip_bfloat16* Qb = (__hip_bfloat16*)d_ws;     // 4*4096*32
    __hip_bfloat16* Kf = Qb + 524288;               // frag-major, 1MB
    __hip_bfloat16* Vf = Kf + 524288;               // frag-major, 1MB
    float* out2   = (float*)(Vf + 524288);          // 4*64*4096
    float* pnum   = out2 + 1048576;                 // 4096 tiles x 1024
    float* pden   = pnum + 4194304;                 // 4096 tiles x 32
    float2* pstats = (float2*)(pden + 131072);      // 64 co x 512 tiles

    qkv_kernel<<<384, 256, 0, stream>>>(cross, mainf, g_w, g_b, th_w, th_b,
                                        ph_w, ph_b, Qb, Kf, Vf);
    attn_part<<<dim3(32, 4, 8), 256, 0, stream>>>(Qb, Kf, Vf, pnum, pden);
    attn_combine<<<dim3(128, 4), 256, 0, stream>>>(pnum, pden, w_w, w_b,
                                                   out2, pstats);
    up_kernel<<<4096, 256, 0, stream>>>(out2, pstats, gamma, beta, mainf, out);
}